// Round 20
// baseline (130.624 us; speedup 1.0000x reference)
//
#include <hip/hip_runtime.h>
#include <math.h>

#define D_MODEL 1024
#define NHEADS 16
#define DH 64
#define BATCH 2
#define SEQ 2048
#define M_TOTAL (BATCH * SEQ)   // 4096

typedef __attribute__((ext_vector_type(8))) short bf16x8;    // MFMA A/B frag (4 VGPR)
typedef __attribute__((ext_vector_type(4))) float f32x4;     // 16x16 C/D frag
typedef __attribute__((ext_vector_type(16))) float f32x16;   // 32x32 C/D frag
typedef __attribute__((ext_vector_type(8))) unsigned short ushort8;
typedef unsigned short u16;
typedef unsigned int u32;

// log2(e)/8 : folds BOTH the 1/sqrt(dk) score scale and the exp->exp2
// conversion into the Q projection epilogue.
#define SCALE_Q 0.18033688f

static __device__ __forceinline__ u16 f2bf(float x) {
  unsigned int u = __float_as_uint(x);
  unsigned int r = (u + 0x7fffu + ((u >> 16) & 1u)) >> 16;   // RNE
  return (u16)r;
}
static __device__ __forceinline__ u32 pk2bf(float a, float b) {
  return (u32)f2bf(a) | ((u32)f2bf(b) << 16);                // RNE packed pair
}
// 3-op half-up pack via v_perm_b32 (bit-identical to the 5-op shift/or form)
static __device__ __forceinline__ u32 pkhu(float a, float b) {
  return __builtin_amdgcn_perm(__float_as_uint(b) + 0x8000u,
                               __float_as_uint(a) + 0x8000u, 0x07060302u);
}
// bare v_exp_f32 (D = 2^S0 per gfx950 ISA)
static __device__ __forceinline__ float exp2fast(float x) {
  return __builtin_amdgcn_exp2f(x);
}

// async global->LDS, 16B per lane
static __device__ __forceinline__ void gl_lds16(const u16* g, u16* l) {
  __builtin_amdgcn_global_load_lds(
      (const __attribute__((address_space(1))) u32*)g,
      (__attribute__((address_space(3))) u32*)l, 16, 0, 0);
}

// ---------------------------------------------------------------------------
// prep: z<3 = fp32->bf16 convert of q/k/v ; z in 3..6 = weight transpose.
// ---------------------------------------------------------------------------
__global__ __launch_bounds__(256) void prep_kernel(
    const float* __restrict__ q, const float* __restrict__ k, const float* __restrict__ v,
    u16* __restrict__ qb, u16* __restrict__ kb, u16* __restrict__ vb,
    const float* __restrict__ w0, const float* __restrict__ w1,
    const float* __restrict__ w2, const float* __restrict__ w3,
    u16* __restrict__ t0, u16* __restrict__ t1,
    u16* __restrict__ t2, u16* __restrict__ t3) {
  __shared__ float tf[64 * 68];
  const int z = blockIdx.z;
  const int tid = threadIdx.x;
  if (z < 3) {
    const float* src = (z == 0) ? q : (z == 1) ? k : v;
    u16* dst = (z == 0) ? qb : (z == 1) ? kb : vb;
    const size_t i = ((size_t)blockIdx.x * 256 + tid) * 8;
    float4 a = *reinterpret_cast<const float4*>(src + i);
    float4 b = *reinterpret_cast<const float4*>(src + i + 4);
    u32 o0 = pk2bf(a.x, a.y), o1 = pk2bf(a.z, a.w);
    u32 o2 = pk2bf(b.x, b.y), o3 = pk2bf(b.z, b.w);
    *reinterpret_cast<uint4*>(dst + i) = make_uint4(o0, o1, o2, o3);
    return;
  }
  if (blockIdx.x >= 256) return;
  const int zz = z - 3;
  const float* w = (zz == 0) ? w0 : (zz == 1) ? w1 : (zz == 2) ? w2 : w3;
  u16* wt = (zz == 0) ? t0 : (zz == 1) ? t1 : (zz == 2) ? t2 : t3;
  const int n0 = (blockIdx.x & 15) * 64, k0 = (blockIdx.x >> 4) * 64;
  const int kl = tid >> 4, nq = (tid & 15) * 4;
#pragma unroll
  for (int c = 0; c < 4; ++c) {
    float4 vv = *reinterpret_cast<const float4*>(
        &w[(size_t)(k0 + kl + c * 16) * 1024 + n0 + nq]);
    *reinterpret_cast<float4*>(&tf[(kl + c * 16) * 68 + nq]) = vv;
  }
  __syncthreads();
  const int n = tid & 63, kq = tid >> 6;
  u32 pk[8];
#pragma unroll
  for (int p = 0; p < 8; ++p) {
    float a = tf[(kq * 16 + 2 * p) * 68 + n];
    float b = tf[(kq * 16 + 2 * p + 1) * 68 + n];
    pk[p] = pk2bf(a, b);
  }
  u16* dst = &wt[(size_t)(n0 + n) * 1024 + k0 + kq * 16];
  *reinterpret_cast<uint4*>(dst) = make_uint4(pk[0], pk[1], pk[2], pk[3]);
  *reinterpret_cast<uint4*>(dst + 8) = make_uint4(pk[4], pk[5], pk[6], pk[7]);
}

// ---------------------------------------------------------------------------
// m97-structure GEMM v2: BM=128, BN=128, BK=32, 4 waves (2x2),
// double-buffered LDS with stage-early; one barrier per K-step.
// ---------------------------------------------------------------------------
__global__ __launch_bounds__(256) void qkv_gemm_kernel(
    const u16* __restrict__ qb, const u16* __restrict__ kb, const u16* __restrict__ vb,
    const u16* __restrict__ wqT, const u16* __restrict__ wkT, const u16* __restrict__ wvT,
    const float* __restrict__ bq, const float* __restrict__ bk, const float* __restrict__ bv,
    u16* __restrict__ qh, u16* __restrict__ kh, u16* __restrict__ vhT) {
  __shared__ u16 lds[16384];          // A: [buf]*4096 | B: 8192 + [buf]*4096

  const int z = blockIdx.z;
  const u16* A  = (z == 0) ? qb : (z == 1) ? kb : vb;
  const u16* BT = (z == 0) ? wqT : (z == 1) ? wkT : wvT;
  const float* bias = (z == 0) ? bq : (z == 1) ? bk : bv;

  int wg = blockIdx.x + 8 * blockIdx.y;
  wg = (wg & 7) * 32 + (wg >> 3);
  const int m0 = (wg >> 3) * 128;
  const int n0 = (wg & 7) * 128;

  const int tid = threadIdx.x;
  const int w = tid >> 6, l = tid & 63;
  const int wr = w >> 1, wc = w & 1;
  const int n = l & 15, g = l >> 4;

  const u16* Ab = A + (size_t)(m0 + w * 16 + (l >> 2)) * 1024 + (l & 3) * 8;
  const u16* Bb = BT + (size_t)(n0 + w * 16 + (l >> 2)) * 1024 + (l & 3) * 8;
  const int wb = w * 512;

  f32x4 acc[4][4];
#pragma unroll
  for (int fm = 0; fm < 4; ++fm)
#pragma unroll
    for (int fn = 0; fn < 4; ++fn) acc[fm][fn] = (f32x4)(0.0f);

  gl_lds16(Ab, lds + wb);
  gl_lds16(Ab + (size_t)64 * 1024, lds + wb + 2048);
  gl_lds16(Bb, lds + 8192 + wb);
  gl_lds16(Bb + (size_t)64 * 1024, lds + 8192 + wb + 2048);
  __syncthreads();

  int cur = 0;
  for (int kk = 0; kk < 1024; kk += 32) {
    u16* sAc = lds + cur * 4096;
    u16* sBc = lds + 8192 + cur * 4096;
    if (kk + 32 < 1024) {
      u16* sAn = lds + (cur ^ 1) * 4096;
      u16* sBn = lds + 8192 + (cur ^ 1) * 4096;
      gl_lds16(Ab + kk + 32, sAn + wb);
      gl_lds16(Ab + kk + 32 + (size_t)64 * 1024, sAn + wb + 2048);
      gl_lds16(Bb + kk + 32, sBn + wb);
      gl_lds16(Bb + kk + 32 + (size_t)64 * 1024, sBn + wb + 2048);
    }
    bf16x8 af[4], bf[4];
#pragma unroll
    for (int f = 0; f < 4; ++f)
      af[f] = *reinterpret_cast<const bf16x8*>(&sAc[(wr * 64 + f * 16 + n) * 32 + g * 8]);
#pragma unroll
    for (int f = 0; f < 4; ++f)
      bf[f] = *reinterpret_cast<const bf16x8*>(&sBc[(wc * 64 + f * 16 + n) * 32 + g * 8]);
#pragma unroll
    for (int fm = 0; fm < 4; ++fm)
#pragma unroll
      for (int fn = 0; fn < 4; ++fn)
        acc[fm][fn] = __builtin_amdgcn_mfma_f32_16x16x32_bf16(af[fm], bf[fn], acc[fm][fn], 0, 0, 0);
    __syncthreads();
    cur ^= 1;
  }

  float bv4[4];
#pragma unroll
  for (int fn = 0; fn < 4; ++fn) bv4[fn] = bias[n0 + wc * 64 + fn * 16 + n];

  if (z < 2) {
    const float scale = (z == 0) ? SCALE_Q : 1.0f;
    u16* dst = (z == 0) ? qh : kh;
#pragma unroll
    for (int fm = 0; fm < 4; ++fm)
#pragma unroll
      for (int fn = 0; fn < 4; ++fn)
#pragma unroll
        for (int rr = 0; rr < 4; ++rr) {
          const int row = m0 + wr * 64 + fm * 16 + g * 4 + rr;
          const int col = n0 + wc * 64 + fn * 16 + n;
          dst[(size_t)row * 1024 + col] = f2bf((acc[fm][fn][rr] + bv4[fn]) * scale);
        }
  } else {
    __syncthreads();
    u16* bw = lds + w * 2304;
    const int hh = (n0 >> 6) + wc;
    const int bb = m0 >> 11;
    const int c = l >> 1, half = l & 1;
    const int sbase = (m0 & 2047) + wr * 64 + half * 32;
#pragma unroll
    for (int p = 0; p < 2; ++p) {
#pragma unroll
      for (int fh = 0; fh < 2; ++fh) {
        const int fn = p * 2 + fh;
#pragma unroll
        for (int fm = 0; fm < 4; ++fm)
#pragma unroll
          for (int rr = 0; rr < 4; ++rr)
            bw[(fh * 16 + n) * 72 + fm * 16 + g * 4 + rr] =
                f2bf(acc[fm][fn][rr] + bv4[fn]);
      }
      __syncthreads();
      u16* gd = vhT + ((size_t)((bb * NHEADS + hh) * DH + p * 32 + c)) * SEQ + sbase;
#pragma unroll
      for (int j = 0; j < 4; ++j)
        *reinterpret_cast<uint4*>(gd + j * 8) =
            *reinterpret_cast<const uint4*>(&bw[c * 72 + half * 32 + j * 8]);
      __syncthreads();
    }
  }
}

// ---------------------------------------------------------------------------
// Output projection v2: dbuf stage-early, BN=64, fp32 out + bias.
// ---------------------------------------------------------------------------
__global__ __launch_bounds__(256) void out_gemm_kernel(
    const u16* __restrict__ aob, const u16* __restrict__ woT,
    const float* __restrict__ bo, float* __restrict__ out) {
  __shared__ u16 lds[12288];          // A: [buf]*4096 at 0 | B: 8192 + [buf]*2048

  int wg = blockIdx.x + 16 * blockIdx.y;
  wg = (wg & 7) * 64 + (wg >> 3);
  const int m0 = (wg >> 4) * 128;
  const int n0 = (wg & 15) * 64;

  const int tid = threadIdx.x;
  const int w = tid >> 6, l = tid & 63;
  const int wr = w >> 1, wc = w & 1;
  const int n = l & 15, g = l >> 4;

  const u16* Ab = aob + (size_t)(m0 + w * 16 + (l >> 2)) * 1024 + (l & 3) * 8;
  const u16* Bb = woT + (size_t)(n0 + w * 16 + (l >> 2)) * 1024 + (l & 3) * 8;
  const int wb = w * 512;

  f32x4 acc[4][2];
#pragma unroll
  for (int fm = 0; fm < 4; ++fm)
#pragma unroll
    for (int fn = 0; fn < 2; ++fn) acc[fm][fn] = (f32x4)(0.0f);

  gl_lds16(Ab, lds + wb);
  gl_lds16(Ab + (size_t)64 * 1024, lds + wb + 2048);
  gl_lds16(Bb, lds + 8192 + wb);
  __syncthreads();

  int cur = 0;
  for (int kk = 0; kk < 1024; kk += 32) {
    u16* sAc = lds + cur * 4096;
    u16* sBc = lds + 8192 + cur * 2048;
    if (kk + 32 < 1024) {
      u16* sAn = lds + (cur ^ 1) * 4096;
      u16* sBn = lds + 8192 + (cur ^ 1) * 2048;
      gl_lds16(Ab + kk + 32, sAn + wb);
      gl_lds16(Ab + kk + 32 + (size_t)64 * 1024, sAn + wb + 2048);
      gl_lds16(Bb + kk + 32, sBn + wb);
    }
    bf16x8 af[4], bf[2];
#pragma unroll
    for (int f = 0; f < 4; ++f)
      af[f] = *reinterpret_cast<const bf16x8*>(&sAc[(wr * 64 + f * 16 + n) * 32 + g * 8]);
#pragma unroll
    for (int f = 0; f < 2; ++f)
      bf[f] = *reinterpret_cast<const bf16x8*>(&sBc[(wc * 32 + f * 16 + n) * 32 + g * 8]);
#pragma unroll
    for (int fm = 0; fm < 4; ++fm)
#pragma unroll
      for (int fn = 0; fn < 2; ++fn)
        acc[fm][fn] = __builtin_amdgcn_mfma_f32_16x16x32_bf16(af[fm], bf[fn], acc[fm][fn], 0, 0, 0);
    __syncthreads();
    cur ^= 1;
  }

  const float b0 = bo[n0 + wc * 32 + n];
  const float b1 = bo[n0 + wc * 32 + 16 + n];
#pragma unroll
  for (int fm = 0; fm < 4; ++fm)
#pragma unroll
    for (int rr = 0; rr < 4; ++rr) {
      const int row = m0 + wr * 64 + fm * 16 + g * 4 + rr;
      out[(size_t)row * 1024 + n0 + wc * 32 + n] = acc[fm][0][rr] + b0;
      out[(size_t)row * 1024 + n0 + wc * 32 + 16 + n] = acc[fm][1][rr] + b1;
    }
}

// ---------------------------------------------------------------------------
// MFMA flash attention v10: v8 math/schedule with 2-WAVE blocks (128 thr,
// 1024 blocks). Each barrier syncs only 2 waves (less skew-wait) and 4
// independent blocks/CU can slip past each other instead of 4-wave lockstep.
// Staging: thread = half K-row + half V-row (4x b128 each), v3-proven.
// ---------------------------------------------------------------------------
#define KT 64
__global__ __launch_bounds__(128, 4) void attn_mfma_kernel(
    const u16* __restrict__ qh, const u16* __restrict__ kh,
    const u16* __restrict__ vhT, u16* __restrict__ aob) {
  const int bid = blockIdx.x;            // 0..1023
  const int xcd = bid & 7;
  const int idx = bid >> 3;              // 0..127
  const int bh = (xcd << 2) | (idx >> 5); // XCD owns 4 heads (K/V L2-resident)
  const int qt = idx & 31;               // 0..31
  const int b = bh >> 4, h = bh & 15;

  const int tid = threadIdx.x;           // 0..127
  const int w = tid >> 6, l = tid & 63;
  const int lr = l & 31;
  const int g1 = l >> 5;
  const int q0 = qt * 64 + w * 32;       // this wave's 32 q-rows

  __shared__ u16 Ks[2][KT * DH];         // [key][dh], xor-swizzled, dbuf
  __shared__ u16 Vs[2][DH * KT];         // [dh][key], xor-swizzled, dbuf

  union { u32 u[4]; bf16x8 v; } onesu;
  onesu.u[0] = onesu.u[1] = onesu.u[2] = onesu.u[3] = 0x3F803F80u;

  bf16x8 qf[4];
#pragma unroll
  for (int kq = 0; kq < 4; ++kq)
    qf[kq] = *reinterpret_cast<const bf16x8*>(
        &qh[((size_t)(b * SEQ + q0 + lr)) * D_MODEL + h * DH + kq * 16 + g1 * 8]);

  f32x16 O0 = (f32x16)(0.0f), O1 = (f32x16)(0.0f), L0 = (f32x16)(0.0f);

  // staging: 128 thr, thread covers half a row (32 u16) of K and of V
  const int srow = tid >> 1, shalf = tid & 1;
  const u16* kp0 = kh + (size_t)(b * SEQ + srow) * D_MODEL + h * DH + shalf * 32;
  const u16* vp0 = vhT + ((size_t)((b * NHEADS + h) * DH + srow)) * SEQ + shalf * 32;
  const int sbase = srow * 64 + shalf * 32;
  const int sxor = (srow & 7) << 3;
  const int rxor = (lr & 7) << 3;

  ushort8 kr[4], vr[4];
#pragma unroll
  for (int c = 0; c < 4; ++c) {
    kr[c] = *reinterpret_cast<const ushort8*>(kp0 + c * 8);
    vr[c] = *reinterpret_cast<const ushort8*>(vp0 + c * 8);
  }
#pragma unroll
  for (int c = 0; c < 4; ++c) {
    const int sidx = (sbase + c * 8) ^ sxor;
    *reinterpret_cast<ushort8*>(&Ks[0][sidx]) = kr[c];
    *reinterpret_cast<ushort8*>(&Vs[0][sidx]) = vr[c];
  }
  __syncthreads();

  int cur = 0;
  for (int jt = 0; jt < SEQ / KT; ++jt) {
    if (jt + 1 < SEQ / KT) {
      const int off = (jt + 1) * KT;
#pragma unroll
      for (int c = 0; c < 4; ++c) {
        kr[c] = *reinterpret_cast<const ushort8*>(kp0 + (size_t)off * D_MODEL + c * 8);
        vr[c] = *reinterpret_cast<const ushort8*>(vp0 + off + c * 8);
      }
    }

    __builtin_amdgcn_s_setprio(1);
    f32x16 St0 = (f32x16)(0.0f), St1 = (f32x16)(0.0f);
#pragma unroll
    for (int kq = 0; kq < 4; ++kq) {
      const int coff = kq * 16 + g1 * 8;
      bf16x8 kf0 = *reinterpret_cast<const bf16x8*>(&Ks[cur][(lr * 64 + coff) ^ rxor]);
      bf16x8 kf1 = *reinterpret_cast<const bf16x8*>(&Ks[cur][((32 + lr) * 64 + coff) ^ rxor]);
      St0 = __builtin_amdgcn_mfma_f32_32x32x16_bf16(kf0, qf[kq], St0, 0, 0, 0);
      St1 = __builtin_amdgcn_mfma_f32_32x32x16_bf16(kf1, qf[kq], St1, 0, 0, 0);
    }
    __builtin_amdgcn_s_setprio(0);

    u32 U0[8], U1[8];
#pragma unroll
    for (int s = 0; s < 8; ++s) {
      float a0 = exp2fast(St0[2 * s]), b0 = exp2fast(St0[2 * s + 1]);
      float a1 = exp2fast(St1[2 * s]), b1 = exp2fast(St1[2 * s + 1]);
      U0[s] = pkhu(a0, b0);
      U1[s] = pkhu(a1, b1);
    }

    __builtin_amdgcn_s_setprio(1);
#pragma unroll
    for (int kb2 = 0; kb2 < 2; ++kb2) {
#pragma unroll
      for (int m16 = 0; m16 < 2; ++m16) {
        union { u32 u[4]; bf16x8 v; } pa;
        if (kb2 == 0) {
          pa.u[0] = U0[m16 * 4 + 0]; pa.u[1] = U0[m16 * 4 + 1];
          pa.u[2] = U0[m16 * 4 + 2]; pa.u[3] = U0[m16 * 4 + 3];
        } else {
          pa.u[0] = U1[m16 * 4 + 0]; pa.u[1] = U1[m16 * 4 + 1];
          pa.u[2] = U1[m16 * 4 + 2]; pa.u[3] = U1[m16 * 4 + 3];
        }
        const int koff = kb2 * 32 + m16 * 16 + g1 * 4;
        union { u32 u[4]; bf16x8 v; } vb0, vb1;
        *reinterpret_cast<uint2*>(&vb0.u[0]) =
            *reinterpret_cast<const uint2*>(&Vs[cur][(lr * 64 + koff) ^ rxor]);
        *reinterpret_cast<uint2*>(&vb0.u[2]) =
            *reinterpret_cast<const uint2*>(&Vs[cur][(lr * 64 + koff + 8) ^ rxor]);
        *reinterpret_cast<uint2*>(&vb1.u[0]) =
            *reinterpret_cast<const uint2*>(&Vs[cur][((32 + lr) * 64 + koff) ^ rxor]);
        *reinterpret_cast<uint2*>(&vb1.u[2]) =
            *reinterpret_cast<const uint2*>(&Vs[cur][((32 + lr) * 64 + koff + 8) ^ rxor]);
        O0 = __builtin_amdgcn_mfma_f32_32x32x16_bf16(pa.v, vb0.v, O0, 0, 0, 0);
        O1 = __builtin_amdgcn_mfma_f32_32x32x16_bf16(pa.v, vb1.v, O1, 0, 0, 0);
        L0 = __builtin_amdgcn_mfma_f32_32x32x16_bf16(pa.v, onesu.v, L0, 0, 0, 0);
      }
    }
    __builtin_amdgcn_s_setprio(0);

    if (jt + 1 < SEQ / KT) {
#pragma unroll
      for (int c = 0; c < 4; ++c) {
        const int sidx = (sbase + c * 8) ^ sxor;
        *reinterpret_cast<ushort8*>(&Ks[cur ^ 1][sidx]) = kr[c];
        *reinterpret_cast<ushort8*>(&Vs[cur ^ 1][sidx]) = vr[c];
      }
    }
    __syncthreads();
    cur ^= 1;
  }

  float invr[16];
#pragma unroll
  for (int r = 0; r < 16; ++r) invr[r] = 0.125f / L0[r];  // second 1/sqrt(dk)
#pragma unroll
  for (int dblk = 0; dblk < 2; ++dblk) {
#pragma unroll
    for (int s = 0; s < 8; ++s) {
      const int r0 = 2 * s, r1 = 2 * s + 1;
      float x0 = (dblk ? O1[r0] : O0[r0]) * invr[r0];
      float x1 = (dblk ? O1[r1] : O0[r1]) * invr[r1];
      const int row0 = q0 + (r0 & 3) + 8 * (r0 >> 2) + 4 * g1;
      const int row1 = q0 + (r1 & 3) + 8 * (r1 >> 2) + 4 * g1;
      const int col = h * DH + dblk * 32 + lr;
      aob[((size_t)(b * SEQ + row0)) * D_MODEL + col] = f2bf(x0);
      aob[((size_t)(b * SEQ + row1)) * D_MODEL + col] = f2bf(x1);
    }
  }
}

// ---------------------------------------------------------------------------
extern "C" void kernel_launch(void* const* d_in, const int* in_sizes, int n_in,
                              void* d_out, int out_size, void* d_ws, size_t ws_size,
                              hipStream_t stream) {
  const float* q  = (const float*)d_in[0];
  const float* k  = (const float*)d_in[1];
  const float* v  = (const float*)d_in[2];
  const float* wq = (const float*)d_in[3];
  const float* bq = (const float*)d_in[4];
  const float* wk = (const float*)d_in[5];
  const float* bk = (const float*)d_in[6];
  const float* wv = (const float*)d_in[7];
  const float* bv = (const float*)d_in[8];
  const float* wo = (const float*)d_in[9];
  const float* bo = (const float*)d_in[10];
  float* out = (float*)d_out;

  const size_t wcount = (size_t)D_MODEL * D_MODEL;
  const size_t tcount = (size_t)M_TOTAL * D_MODEL;
  u16* wqT = (u16*)d_ws;
  u16* wkT = wqT + wcount;
  u16* wvT = wkT + wcount;
  u16* woT = wvT + wcount;
  u16* qb  = woT + wcount;
  u16* kb  = qb + tcount;
  u16* vb  = kb + tcount;
  u16* qh  = vb + tcount;
  u16* kh  = qh + tcount;
  u16* vhT = kh + tcount;
  u16* aob = qb;                  // alias: qb dead before attn writes aob

  dim3 blk(256);

  prep_kernel<<<dim3(2048, 1, 7), blk, 0, stream>>>(
      q, k, v, qb, kb, vb, wq, wk, wv, wo, wqT, wkT, wvT, woT);

  qkv_gemm_kernel<<<dim3(8, 32, 3), blk, 0, stream>>>(
      qb, kb, vb, wqT, wkT, wvT, bq, bk, bv, qh, kh, vhT);

  attn_mfma_kernel<<<dim3(1024), dim3(128), 0, stream>>>(qh, kh, vhT, aob);

  out_gemm_kernel<<<dim3(16, 32), blk, 0, stream>>>(aob, woT, bo, out);
}

// Round 21
// 118.341 us; speedup vs baseline: 1.1038x; 1.1038x over previous
//
#include <hip/hip_runtime.h>
#include <math.h>

#define D_MODEL 1024
#define NHEADS 16
#define DH 64
#define BATCH 2
#define SEQ 2048
#define M_TOTAL (BATCH * SEQ)   // 4096

typedef __attribute__((ext_vector_type(8))) short bf16x8;    // MFMA A/B frag (4 VGPR)
typedef __attribute__((ext_vector_type(4))) float f32x4;     // 16x16 C/D frag
typedef __attribute__((ext_vector_type(16))) float f32x16;   // 32x32 C/D frag
typedef __attribute__((ext_vector_type(8))) unsigned short ushort8;
typedef unsigned short u16;
typedef unsigned int u32;

// log2(e)/8 : folds BOTH the 1/sqrt(dk) score scale and the exp->exp2
// conversion into the Q projection epilogue.
#define SCALE_Q 0.18033688f

static __device__ __forceinline__ u16 f2bf(float x) {
  unsigned int u = __float_as_uint(x);
  unsigned int r = (u + 0x7fffu + ((u >> 16) & 1u)) >> 16;   // RNE
  return (u16)r;
}
static __device__ __forceinline__ u32 pk2bf(float a, float b) {
  return (u32)f2bf(a) | ((u32)f2bf(b) << 16);                // RNE packed pair
}
// 3-op half-up pack via v_perm_b32 (bit-identical to the 5-op shift/or form)
static __device__ __forceinline__ u32 pkhu(float a, float b) {
  return __builtin_amdgcn_perm(__float_as_uint(b) + 0x8000u,
                               __float_as_uint(a) + 0x8000u, 0x07060302u);
}
// bare v_exp_f32 (D = 2^S0 per gfx950 ISA)
static __device__ __forceinline__ float exp2fast(float x) {
  return __builtin_amdgcn_exp2f(x);
}

// async global->LDS, 16B per lane
static __device__ __forceinline__ void gl_lds16(const u16* g, u16* l) {
  __builtin_amdgcn_global_load_lds(
      (const __attribute__((address_space(1))) u32*)g,
      (__attribute__((address_space(3))) u32*)l, 16, 0, 0);
}

// ---------------------------------------------------------------------------
// prep: z<3 = fp32->bf16 convert of q/k/v ; z in 3..6 = weight transpose.
// ---------------------------------------------------------------------------
__global__ __launch_bounds__(256) void prep_kernel(
    const float* __restrict__ q, const float* __restrict__ k, const float* __restrict__ v,
    u16* __restrict__ qb, u16* __restrict__ kb, u16* __restrict__ vb,
    const float* __restrict__ w0, const float* __restrict__ w1,
    const float* __restrict__ w2, const float* __restrict__ w3,
    u16* __restrict__ t0, u16* __restrict__ t1,
    u16* __restrict__ t2, u16* __restrict__ t3) {
  __shared__ float tf[64 * 68];
  const int z = blockIdx.z;
  const int tid = threadIdx.x;
  if (z < 3) {
    const float* src = (z == 0) ? q : (z == 1) ? k : v;
    u16* dst = (z == 0) ? qb : (z == 1) ? kb : vb;
    const size_t i = ((size_t)blockIdx.x * 256 + tid) * 8;
    float4 a = *reinterpret_cast<const float4*>(src + i);
    float4 b = *reinterpret_cast<const float4*>(src + i + 4);
    u32 o0 = pk2bf(a.x, a.y), o1 = pk2bf(a.z, a.w);
    u32 o2 = pk2bf(b.x, b.y), o3 = pk2bf(b.z, b.w);
    *reinterpret_cast<uint4*>(dst + i) = make_uint4(o0, o1, o2, o3);
    return;
  }
  if (blockIdx.x >= 256) return;
  const int zz = z - 3;
  const float* w = (zz == 0) ? w0 : (zz == 1) ? w1 : (zz == 2) ? w2 : w3;
  u16* wt = (zz == 0) ? t0 : (zz == 1) ? t1 : (zz == 2) ? t2 : t3;
  const int n0 = (blockIdx.x & 15) * 64, k0 = (blockIdx.x >> 4) * 64;
  const int kl = tid >> 4, nq = (tid & 15) * 4;
#pragma unroll
  for (int c = 0; c < 4; ++c) {
    float4 vv = *reinterpret_cast<const float4*>(
        &w[(size_t)(k0 + kl + c * 16) * 1024 + n0 + nq]);
    *reinterpret_cast<float4*>(&tf[(kl + c * 16) * 68 + nq]) = vv;
  }
  __syncthreads();
  const int n = tid & 63, kq = tid >> 6;
  u32 pk[8];
#pragma unroll
  for (int p = 0; p < 8; ++p) {
    float a = tf[(kq * 16 + 2 * p) * 68 + n];
    float b = tf[(kq * 16 + 2 * p + 1) * 68 + n];
    pk[p] = pk2bf(a, b);
  }
  u16* dst = &wt[(size_t)(n0 + n) * 1024 + k0 + kq * 16];
  *reinterpret_cast<uint4*>(dst) = make_uint4(pk[0], pk[1], pk[2], pk[3]);
  *reinterpret_cast<uint4*>(dst + 8) = make_uint4(pk[4], pk[5], pk[6], pk[7]);
}

// ---------------------------------------------------------------------------
// m97-structure GEMM v2: BM=128, BN=128, BK=32, 4 waves (2x2),
// double-buffered LDS with stage-early; one barrier per K-step.
// ---------------------------------------------------------------------------
__global__ __launch_bounds__(256) void qkv_gemm_kernel(
    const u16* __restrict__ qb, const u16* __restrict__ kb, const u16* __restrict__ vb,
    const u16* __restrict__ wqT, const u16* __restrict__ wkT, const u16* __restrict__ wvT,
    const float* __restrict__ bq, const float* __restrict__ bk, const float* __restrict__ bv,
    u16* __restrict__ qh, u16* __restrict__ kh, u16* __restrict__ vhT) {
  __shared__ u16 lds[16384];          // A: [buf]*4096 | B: 8192 + [buf]*4096

  const int z = blockIdx.z;
  const u16* A  = (z == 0) ? qb : (z == 1) ? kb : vb;
  const u16* BT = (z == 0) ? wqT : (z == 1) ? wkT : wvT;
  const float* bias = (z == 0) ? bq : (z == 1) ? bk : bv;

  int wg = blockIdx.x + 8 * blockIdx.y;
  wg = (wg & 7) * 32 + (wg >> 3);
  const int m0 = (wg >> 3) * 128;
  const int n0 = (wg & 7) * 128;

  const int tid = threadIdx.x;
  const int w = tid >> 6, l = tid & 63;
  const int wr = w >> 1, wc = w & 1;
  const int n = l & 15, g = l >> 4;

  const u16* Ab = A + (size_t)(m0 + w * 16 + (l >> 2)) * 1024 + (l & 3) * 8;
  const u16* Bb = BT + (size_t)(n0 + w * 16 + (l >> 2)) * 1024 + (l & 3) * 8;
  const int wb = w * 512;

  f32x4 acc[4][4];
#pragma unroll
  for (int fm = 0; fm < 4; ++fm)
#pragma unroll
    for (int fn = 0; fn < 4; ++fn) acc[fm][fn] = (f32x4)(0.0f);

  gl_lds16(Ab, lds + wb);
  gl_lds16(Ab + (size_t)64 * 1024, lds + wb + 2048);
  gl_lds16(Bb, lds + 8192 + wb);
  gl_lds16(Bb + (size_t)64 * 1024, lds + 8192 + wb + 2048);
  __syncthreads();

  int cur = 0;
  for (int kk = 0; kk < 1024; kk += 32) {
    u16* sAc = lds + cur * 4096;
    u16* sBc = lds + 8192 + cur * 4096;
    if (kk + 32 < 1024) {
      u16* sAn = lds + (cur ^ 1) * 4096;
      u16* sBn = lds + 8192 + (cur ^ 1) * 4096;
      gl_lds16(Ab + kk + 32, sAn + wb);
      gl_lds16(Ab + kk + 32 + (size_t)64 * 1024, sAn + wb + 2048);
      gl_lds16(Bb + kk + 32, sBn + wb);
      gl_lds16(Bb + kk + 32 + (size_t)64 * 1024, sBn + wb + 2048);
    }
    bf16x8 af[4], bf[4];
#pragma unroll
    for (int f = 0; f < 4; ++f)
      af[f] = *reinterpret_cast<const bf16x8*>(&sAc[(wr * 64 + f * 16 + n) * 32 + g * 8]);
#pragma unroll
    for (int f = 0; f < 4; ++f)
      bf[f] = *reinterpret_cast<const bf16x8*>(&sBc[(wc * 64 + f * 16 + n) * 32 + g * 8]);
#pragma unroll
    for (int fm = 0; fm < 4; ++fm)
#pragma unroll
      for (int fn = 0; fn < 4; ++fn)
        acc[fm][fn] = __builtin_amdgcn_mfma_f32_16x16x32_bf16(af[fm], bf[fn], acc[fm][fn], 0, 0, 0);
    __syncthreads();
    cur ^= 1;
  }

  float bv4[4];
#pragma unroll
  for (int fn = 0; fn < 4; ++fn) bv4[fn] = bias[n0 + wc * 64 + fn * 16 + n];

  if (z < 2) {
    const float scale = (z == 0) ? SCALE_Q : 1.0f;
    u16* dst = (z == 0) ? qh : kh;
#pragma unroll
    for (int fm = 0; fm < 4; ++fm)
#pragma unroll
      for (int fn = 0; fn < 4; ++fn)
#pragma unroll
        for (int rr = 0; rr < 4; ++rr) {
          const int row = m0 + wr * 64 + fm * 16 + g * 4 + rr;
          const int col = n0 + wc * 64 + fn * 16 + n;
          dst[(size_t)row * 1024 + col] = f2bf((acc[fm][fn][rr] + bv4[fn]) * scale);
        }
  } else {
    __syncthreads();
    u16* bw = lds + w * 2304;
    const int hh = (n0 >> 6) + wc;
    const int bb = m0 >> 11;
    const int c = l >> 1, half = l & 1;
    const int sbase = (m0 & 2047) + wr * 64 + half * 32;
#pragma unroll
    for (int p = 0; p < 2; ++p) {
#pragma unroll
      for (int fh = 0; fh < 2; ++fh) {
        const int fn = p * 2 + fh;
#pragma unroll
        for (int fm = 0; fm < 4; ++fm)
#pragma unroll
          for (int rr = 0; rr < 4; ++rr)
            bw[(fh * 16 + n) * 72 + fm * 16 + g * 4 + rr] =
                f2bf(acc[fm][fn][rr] + bv4[fn]);
      }
      __syncthreads();
      u16* gd = vhT + ((size_t)((bb * NHEADS + hh) * DH + p * 32 + c)) * SEQ + sbase;
#pragma unroll
      for (int j = 0; j < 4; ++j)
        *reinterpret_cast<uint4*>(gd + j * 8) =
            *reinterpret_cast<const uint4*>(&bw[c * 72 + half * 32 + j * 8]);
      __syncthreads();
    }
  }
}

// ---------------------------------------------------------------------------
// Output projection v2: dbuf stage-early, BN=64, fp32 out + bias.
// ---------------------------------------------------------------------------
__global__ __launch_bounds__(256) void out_gemm_kernel(
    const u16* __restrict__ aob, const u16* __restrict__ woT,
    const float* __restrict__ bo, float* __restrict__ out) {
  __shared__ u16 lds[12288];          // A: [buf]*4096 at 0 | B: 8192 + [buf]*2048

  int wg = blockIdx.x + 16 * blockIdx.y;
  wg = (wg & 7) * 64 + (wg >> 3);
  const int m0 = (wg >> 4) * 128;
  const int n0 = (wg & 15) * 64;

  const int tid = threadIdx.x;
  const int w = tid >> 6, l = tid & 63;
  const int wr = w >> 1, wc = w & 1;
  const int n = l & 15, g = l >> 4;

  const u16* Ab = aob + (size_t)(m0 + w * 16 + (l >> 2)) * 1024 + (l & 3) * 8;
  const u16* Bb = woT + (size_t)(n0 + w * 16 + (l >> 2)) * 1024 + (l & 3) * 8;
  const int wb = w * 512;

  f32x4 acc[4][2];
#pragma unroll
  for (int fm = 0; fm < 4; ++fm)
#pragma unroll
    for (int fn = 0; fn < 2; ++fn) acc[fm][fn] = (f32x4)(0.0f);

  gl_lds16(Ab, lds + wb);
  gl_lds16(Ab + (size_t)64 * 1024, lds + wb + 2048);
  gl_lds16(Bb, lds + 8192 + wb);
  __syncthreads();

  int cur = 0;
  for (int kk = 0; kk < 1024; kk += 32) {
    u16* sAc = lds + cur * 4096;
    u16* sBc = lds + 8192 + cur * 2048;
    if (kk + 32 < 1024) {
      u16* sAn = lds + (cur ^ 1) * 4096;
      u16* sBn = lds + 8192 + (cur ^ 1) * 2048;
      gl_lds16(Ab + kk + 32, sAn + wb);
      gl_lds16(Ab + kk + 32 + (size_t)64 * 1024, sAn + wb + 2048);
      gl_lds16(Bb + kk + 32, sBn + wb);
    }
    bf16x8 af[4], bf[2];
#pragma unroll
    for (int f = 0; f < 4; ++f)
      af[f] = *reinterpret_cast<const bf16x8*>(&sAc[(wr * 64 + f * 16 + n) * 32 + g * 8]);
#pragma unroll
    for (int f = 0; f < 2; ++f)
      bf[f] = *reinterpret_cast<const bf16x8*>(&sBc[(wc * 32 + f * 16 + n) * 32 + g * 8]);
#pragma unroll
    for (int fm = 0; fm < 4; ++fm)
#pragma unroll
      for (int fn = 0; fn < 2; ++fn)
        acc[fm][fn] = __builtin_amdgcn_mfma_f32_16x16x32_bf16(af[fm], bf[fn], acc[fm][fn], 0, 0, 0);
    __syncthreads();
    cur ^= 1;
  }

  const float b0 = bo[n0 + wc * 32 + n];
  const float b1 = bo[n0 + wc * 32 + 16 + n];
#pragma unroll
  for (int fm = 0; fm < 4; ++fm)
#pragma unroll
    for (int rr = 0; rr < 4; ++rr) {
      const int row = m0 + wr * 64 + fm * 16 + g * 4 + rr;
      out[(size_t)row * 1024 + n0 + wc * 32 + n] = acc[fm][0][rr] + b0;
      out[(size_t)row * 1024 + n0 + wc * 32 + 16 + n] = acc[fm][1][rr] + b1;
    }
}

// ---------------------------------------------------------------------------
// MFMA flash attention v11: v8 math/geometry (4 waves x 32 q-rows, 512
// blocks) with KT=128 split into TWO 64-key sub-phases per barrier: same
// register footprint as v8 (St/U reused across halves), but the per-tile
// barrier+drain cost amortizes over 2x compute (barriers 32 -> 16).
// Key order per q-row unchanged -> bit-identical accumulation vs v8.
// ---------------------------------------------------------------------------
__global__ __launch_bounds__(256, 2) void attn_mfma_kernel(
    const u16* __restrict__ qh, const u16* __restrict__ kh,
    const u16* __restrict__ vhT, u16* __restrict__ aob) {
  const int bid = blockIdx.x;            // 0..511
  const int xcd = bid & 7;
  const int idx = bid >> 3;              // 0..63
  const int bh = (xcd << 2) | (idx >> 4); // XCD owns 4 heads (K/V L2-resident)
  const int qt = idx & 15;               // 0..15
  const int b = bh >> 4, h = bh & 15;

  const int tid = threadIdx.x;
  const int w = tid >> 6, l = tid & 63;
  const int lr = l & 31;
  const int g1 = l >> 5;
  const int q0 = qt * 128 + w * 32;

  __shared__ u16 Ks[2][2][64 * DH];      // [buf][half][key*64dh], xor-swizzled
  __shared__ u16 Vs[2][2][DH * 64];      // [buf][half][dh*64key], xor-swizzled

  union { u32 u[4]; bf16x8 v; } onesu;
  onesu.u[0] = onesu.u[1] = onesu.u[2] = onesu.u[3] = 0x3F803F80u;

  bf16x8 qf[4];
#pragma unroll
  for (int kq = 0; kq < 4; ++kq)
    qf[kq] = *reinterpret_cast<const bf16x8*>(
        &qh[((size_t)(b * SEQ + q0 + lr)) * D_MODEL + h * DH + kq * 16 + g1 * 8]);

  f32x16 O0 = (f32x16)(0.0f), O1 = (f32x16)(0.0f), L0 = (f32x16)(0.0f);

  // staging: 256 thr; per half, thread covers 16 u16 (quarter K-row / V-row)
  const int srow = tid >> 2, sq = tid & 3;
  const u16* kp0 = kh + (size_t)(b * SEQ + srow) * D_MODEL + h * DH + sq * 16;
  const u16* vp0 = vhT + ((size_t)((b * NHEADS + h) * DH + srow)) * SEQ + sq * 16;
  const int sbase = srow * 64 + sq * 16;
  const int sxor = (srow & 7) << 3;
  const int rxor = (lr & 7) << 3;

  // kr/vr: [half*2 + c]
  ushort8 kr[4], vr[4];
#pragma unroll
  for (int hh = 0; hh < 2; ++hh)
#pragma unroll
    for (int c = 0; c < 2; ++c) {
      kr[hh * 2 + c] = *reinterpret_cast<const ushort8*>(
          kp0 + (size_t)(hh * 64) * D_MODEL + c * 8);
      vr[hh * 2 + c] = *reinterpret_cast<const ushort8*>(vp0 + hh * 64 + c * 8);
    }
#pragma unroll
  for (int hh = 0; hh < 2; ++hh)
#pragma unroll
    for (int c = 0; c < 2; ++c) {
      const int sidx = (sbase + c * 8) ^ sxor;
      *reinterpret_cast<ushort8*>(&Ks[0][hh][sidx]) = kr[hh * 2 + c];
      *reinterpret_cast<ushort8*>(&Vs[0][hh][sidx]) = vr[hh * 2 + c];
    }
  __syncthreads();

  int cur = 0;
  const int NT = SEQ / 128;              // 16 iterations, 1 barrier each
  for (int jt = 0; jt < NT; ++jt) {
    if (jt + 1 < NT) {
      const size_t koff = (size_t)((jt + 1) * 128) * D_MODEL;
      const int voff = (jt + 1) * 128;
#pragma unroll
      for (int hh = 0; hh < 2; ++hh)
#pragma unroll
        for (int c = 0; c < 2; ++c) {
          kr[hh * 2 + c] = *reinterpret_cast<const ushort8*>(
              kp0 + koff + (size_t)(hh * 64) * D_MODEL + c * 8);
          vr[hh * 2 + c] = *reinterpret_cast<const ushort8*>(
              vp0 + voff + hh * 64 + c * 8);
        }
    }

#pragma unroll
    for (int half = 0; half < 2; ++half) {
      // ---- St = K . Q^T (swapped), 64 keys of this half ----
      __builtin_amdgcn_s_setprio(1);
      f32x16 St0 = (f32x16)(0.0f), St1 = (f32x16)(0.0f);
#pragma unroll
      for (int kq = 0; kq < 4; ++kq) {
        const int coff = kq * 16 + g1 * 8;
        bf16x8 kf0 = *reinterpret_cast<const bf16x8*>(
            &Ks[cur][half][(lr * 64 + coff) ^ rxor]);
        bf16x8 kf1 = *reinterpret_cast<const bf16x8*>(
            &Ks[cur][half][((32 + lr) * 64 + coff) ^ rxor]);
        St0 = __builtin_amdgcn_mfma_f32_32x32x16_bf16(kf0, qf[kq], St0, 0, 0, 0);
        St1 = __builtin_amdgcn_mfma_f32_32x32x16_bf16(kf1, qf[kq], St1, 0, 0, 0);
      }
      __builtin_amdgcn_s_setprio(0);

      // ---- P = exp2(St), 3-op half-up pack ----
      u32 U0[8], U1[8];
#pragma unroll
      for (int s = 0; s < 8; ++s) {
        float a0 = exp2fast(St0[2 * s]), b0 = exp2fast(St0[2 * s + 1]);
        float a1 = exp2fast(St1[2 * s]), b1 = exp2fast(St1[2 * s + 1]);
        U0[s] = pkhu(a0, b0);
        U1[s] = pkhu(a1, b1);
      }

      // ---- PV + L, kappa-permuted ----
      __builtin_amdgcn_s_setprio(1);
#pragma unroll
      for (int kb2 = 0; kb2 < 2; ++kb2) {
#pragma unroll
        for (int m16 = 0; m16 < 2; ++m16) {
          union { u32 u[4]; bf16x8 v; } pa;
          if (kb2 == 0) {
            pa.u[0] = U0[m16 * 4 + 0]; pa.u[1] = U0[m16 * 4 + 1];
            pa.u[2] = U0[m16 * 4 + 2]; pa.u[3] = U0[m16 * 4 + 3];
          } else {
            pa.u[0] = U1[m16 * 4 + 0]; pa.u[1] = U1[m16 * 4 + 1];
            pa.u[2] = U1[m16 * 4 + 2]; pa.u[3] = U1[m16 * 4 + 3];
          }
          const int koff = kb2 * 32 + m16 * 16 + g1 * 4;
          union { u32 u[4]; bf16x8 v; } vb0, vb1;
          *reinterpret_cast<uint2*>(&vb0.u[0]) =
              *reinterpret_cast<const uint2*>(&Vs[cur][half][(lr * 64 + koff) ^ rxor]);
          *reinterpret_cast<uint2*>(&vb0.u[2]) =
              *reinterpret_cast<const uint2*>(&Vs[cur][half][(lr * 64 + koff + 8) ^ rxor]);
          *reinterpret_cast<uint2*>(&vb1.u[0]) =
              *reinterpret_cast<const uint2*>(&Vs[cur][half][((32 + lr) * 64 + koff) ^ rxor]);
          *reinterpret_cast<uint2*>(&vb1.u[2]) =
              *reinterpret_cast<const uint2*>(&Vs[cur][half][((32 + lr) * 64 + koff + 8) ^ rxor]);
          O0 = __builtin_amdgcn_mfma_f32_32x32x16_bf16(pa.v, vb0.v, O0, 0, 0, 0);
          O1 = __builtin_amdgcn_mfma_f32_32x32x16_bf16(pa.v, vb1.v, O1, 0, 0, 0);
          L0 = __builtin_amdgcn_mfma_f32_32x32x16_bf16(pa.v, onesu.v, L0, 0, 0, 0);
        }
      }
      __builtin_amdgcn_s_setprio(0);
    }

    // ---- write prefetched 128-key tile, single barrier ----
    if (jt + 1 < NT) {
#pragma unroll
      for (int hh = 0; hh < 2; ++hh)
#pragma unroll
        for (int c = 0; c < 2; ++c) {
          const int sidx = (sbase + c * 8) ^ sxor;
          *reinterpret_cast<ushort8*>(&Ks[cur ^ 1][hh][sidx]) = kr[hh * 2 + c];
          *reinterpret_cast<ushort8*>(&Vs[cur ^ 1][hh][sidx]) = vr[hh * 2 + c];
        }
    }
    __syncthreads();
    cur ^= 1;
  }

  float invr[16];
#pragma unroll
  for (int r = 0; r < 16; ++r) invr[r] = 0.125f / L0[r];  // second 1/sqrt(dk)
#pragma unroll
  for (int dblk = 0; dblk < 2; ++dblk) {
#pragma unroll
    for (int s = 0; s < 8; ++s) {
      const int r0 = 2 * s, r1 = 2 * s + 1;
      float x0 = (dblk ? O1[r0] : O0[r0]) * invr[r0];
      float x1 = (dblk ? O1[r1] : O0[r1]) * invr[r1];
      const int row0 = q0 + (r0 & 3) + 8 * (r0 >> 2) + 4 * g1;
      const int row1 = q0 + (r1 & 3) + 8 * (r1 >> 2) + 4 * g1;
      const int col = h * DH + dblk * 32 + lr;
      aob[((size_t)(b * SEQ + row0)) * D_MODEL + col] = f2bf(x0);
      aob[((size_t)(b * SEQ + row1)) * D_MODEL + col] = f2bf(x1);
    }
  }
}

// ---------------------------------------------------------------------------
extern "C" void kernel_launch(void* const* d_in, const int* in_sizes, int n_in,
                              void* d_out, int out_size, void* d_ws, size_t ws_size,
                              hipStream_t stream) {
  const float* q  = (const float*)d_in[0];
  const float* k  = (const float*)d_in[1];
  const float* v  = (const float*)d_in[2];
  const float* wq = (const float*)d_in[3];
  const float* bq = (const float*)d_in[4];
  const float* wk = (const float*)d_in[5];
  const float* bk = (const float*)d_in[6];
  const float* wv = (const float*)d_in[7];
  const float* bv = (const float*)d_in[8];
  const float* wo = (const float*)d_in[9];
  const float* bo = (const float*)d_in[10];
  float* out = (float*)d_out;

  const size_t wcount = (size_t)D_MODEL * D_MODEL;
  const size_t tcount = (size_t)M_TOTAL * D_MODEL;
  u16* wqT = (u16*)d_ws;
  u16* wkT = wqT + wcount;
  u16* wvT = wkT + wcount;
  u16* woT = wvT + wcount;
  u16* qb  = woT + wcount;
  u16* kb  = qb + tcount;
  u16* vb  = kb + tcount;
  u16* qh  = vb + tcount;
  u16* kh  = qh + tcount;
  u16* vhT = kh + tcount;
  u16* aob = qb;                  // alias: qb dead before attn writes aob

  dim3 blk(256);

  prep_kernel<<<dim3(2048, 1, 7), blk, 0, stream>>>(
      q, k, v, qb, kb, vb, wq, wk, wv, wo, wqT, wkT, wvT, woT);

  qkv_gemm_kernel<<<dim3(8, 32, 3), blk, 0, stream>>>(
      qb, kb, vb, wqT, wkT, wvT, bq, bk, bv, qh, kh, vhT);

  attn_mfma_kernel<<<dim3(512), blk, 0, stream>>>(qh, kh, vhT, aob);

  out_gemm_kernel<<<dim3(16, 32), blk, 0, stream>>>(aob, woT, bo, out);
}